// Round 4
// baseline (165.393 us; speedup 1.0000x reference)
//
#include <hip/hip_runtime.h>
#include <math.h>

// Problem constants (fixed by setup_inputs)
#define BB    8
#define DD    64
#define NPIX  32768
#define KK    19
#define PP    5
#define KP    95
#define KPAD  96

typedef _Float16 half8 __attribute__((ext_vector_type(8)));
typedef float f32x4 __attribute__((ext_vector_type(4)));

#define WAVE_LDS 16384   // per-wave private region: u-tile 32 rows x 512 B; logp [96][33] f32 aliases it

// ---------------------------------------------------------------------------
// Prep: bake coefficients (unchanged from round 3; verified).
//   k-interleaved: C[j][2d] = mu_n*inv2 (x-term), C[j][2d+1] = -0.5*inv2 (x^2)
//   split fp16: Ch = f16(C), Cl = f16(C - Ch); cst[j]; j=95 row zeroed;
//   scal = {sum(w^2), sum(w*b), sum(b^2)} for folding LN+l2 into affine u.
// ---------------------------------------------------------------------------
__global__ __launch_bounds__(64) void gmm_prep(
        const float* __restrict__ means, const float* __restrict__ diag,
        const float* __restrict__ feat_w, const float* __restrict__ feat_b,
        _Float16* __restrict__ Ch, _Float16* __restrict__ Cl,
        float* __restrict__ cst, float* __restrict__ scal) {
    int j = blockIdx.x;
    int d = threadIdx.x;
    if (j < KP) {
        float mu = means[j * DD + d];
        float sc = diag[j * DD + d];
        float ss = mu * mu;
        #pragma unroll
        for (int off = 32; off; off >>= 1) ss += __shfl_xor(ss, off);
        float inv = 1.f / fmaxf(sqrtf(ss), 1e-12f);
        float mn = mu * inv;
        float i2 = 1.f / (sc * sc);
        float A = mn * i2;
        float B = -0.5f * i2;
        _Float16 ah = (_Float16)A; _Float16 al = (_Float16)(A - (float)ah);
        _Float16 bh = (_Float16)B; _Float16 bl = (_Float16)(B - (float)bh);
        Ch[j * 128 + 2 * d]     = ah;
        Ch[j * 128 + 2 * d + 1] = bh;
        Cl[j * 128 + 2 * d]     = al;
        Cl[j * 128 + 2 * d + 1] = bl;
        float c1 = mn * mn * i2;
        float c2 = logf(sc);
        #pragma unroll
        for (int off = 32; off; off >>= 1) {
            c1 += __shfl_xor(c1, off);
            c2 += __shfl_xor(c2, off);
        }
        if (d == 0) cst[j] = -0.5f * c1 - c2 - 58.8120661251f; // 32*ln(2*pi)
    } else {
        Ch[95 * 128 + 2 * d] = (_Float16)0.f; Ch[95 * 128 + 2 * d + 1] = (_Float16)0.f;
        Cl[95 * 128 + 2 * d] = (_Float16)0.f; Cl[95 * 128 + 2 * d + 1] = (_Float16)0.f;
        float w = feat_w[d], b = feat_b[d];
        float s0 = w * w, s1 = w * b, s2 = b * b;
        #pragma unroll
        for (int off = 32; off; off >>= 1) {
            s0 += __shfl_xor(s0, off);
            s1 += __shfl_xor(s1, off);
            s2 += __shfl_xor(s2, off);
        }
        if (d == 0) { cst[95] = 0.f; scal[0] = s0; scal[1] = s1; scal[2] = s2; }
    }
}

// ---------------------------------------------------------------------------
// Main: 128 threads = 2 fully-independent waves, 32 px each. ZERO barriers.
//   lane = (px = lane&31, h = lane>>5 owning d in [32h,32h+32))
//   moments via shfl_xor(32); u-tile in wave-private LDS (XOR-swizzled 16B
//   cols -> b128 at the 8-cyc floor); all 16 B-frags to regs; logp [96][33]
//   aliases the dead u region; per-wave epilogue (k-split across lane halves).
// ---------------------------------------------------------------------------
__global__ __launch_bounds__(128, 2) void gmm_main(
        const float* __restrict__ bf,
        const float* __restrict__ feat_w, const float* __restrict__ feat_b,
        const float* __restrict__ mask_w, const float* __restrict__ mask_b,
        const _Float16* __restrict__ Ch, const _Float16* __restrict__ Cl,
        const float* __restrict__ cst, const float* __restrict__ scal,
        float* __restrict__ out) {
    __shared__ __align__(16) unsigned char smem[2 * WAVE_LDS];

    const int tid  = threadIdx.x;
    const int w    = tid >> 6;
    const int lane = tid & 63;
    const int px   = lane & 31;
    const int h    = lane >> 5;
    const int m15  = lane & 15;
    const int q    = lane >> 4;
    const int bidx = blockIdx.x;
    const int b    = bidx >> 9;                        // 512 blocks per image
    const int n0   = ((bidx & 511) << 6) + (w << 5);   // wave's first pixel
    unsigned char* wbase = smem + w * WAVE_LDS;

    // ---- load x: own 32 d's, coalesced (consecutive px per lane-half) ----
    const int dbase = h * 32;
    const float* xp = bf + (size_t)b * (DD * NPIX) + (size_t)dbase * NPIX + n0 + px;
    float xs[32];
    #pragma unroll
    for (int i = 0; i < 32; ++i) xs[i] = xp[(size_t)i * NPIX];

    // ---- moments (in-wave; combine halves with one shfl each) ----
    float S1 = 0.f, S2 = 0.f, S3 = 0.f, S4 = 0.f, S5 = 0.f;
    #pragma unroll
    for (int i = 0; i < 32; ++i) {
        float wd = feat_w[dbase + i];
        float bd = feat_b[dbase + i];
        float x  = xs[i];
        float t  = wd * x;
        S1 += x;
        S2 = fmaf(x, x, S2);
        S3 = fmaf(t, t, S3);
        S4 = fmaf(t, wd, S4);
        S5 = fmaf(t, bd, S5);
    }
    S1 += __shfl_xor(S1, 32);
    S2 += __shfl_xor(S2, 32);
    S3 += __shfl_xor(S3, 32);
    S4 += __shfl_xor(S4, 32);
    S5 += __shfl_xor(S5, 32);

    const float W2 = scal[0], WB = scal[1], B2 = scal[2];
    float mu  = S1 * (1.f / 64.f);
    float var = fmaxf(S2 * (1.f / 64.f) - mu * mu, 0.f);
    float r   = rsqrtf(var + 1e-5f);
    float Sy2 = r * r * (S3 - 2.f * mu * S4 + mu * mu * W2)
              + 2.f * r * (S5 - mu * WB) + B2;
    float invn  = 1.f / fmaxf(sqrtf(fmaxf(Sy2, 0.f)), 1e-12f);
    float alpha = invn * r;
    float e = invn;
    float f = -alpha * mu;

    // ---- build split-fp16 u row (XOR-swizzled 16B columns) ----
    {
        unsigned char* rowp = wbase + px * 512;
        #pragma unroll
        for (int g = 0; g < 8; ++g) {
            half8 vh, vl;
            #pragma unroll
            for (int jj = 0; jj < 4; ++jj) {
                int d = dbase + 4 * g + jj;
                float wd = feat_w[d];
                float bd = feat_b[d];
                float c  = fmaf(f, wd, e * bd);
                float u  = fmaf(alpha * wd, xs[4 * g + jj], c);
                float us = u * u;
                _Float16 uh = (_Float16)u;  _Float16 ul = (_Float16)(u  - (float)uh);
                _Float16 qh = (_Float16)us; _Float16 ql = (_Float16)(us - (float)qh);
                vh[2 * jj] = uh; vh[2 * jj + 1] = qh;
                vl[2 * jj] = ul; vl[2 * jj + 1] = ql;
            }
            const int col = (8 * h + g) ^ (px & 15);
            *(half8*)(rowp + (col << 4))       = vh;
            *(half8*)(rowp + 256 + (col << 4)) = vl;
        }
    }

    // ---- load ALL u B-fragments to regs (u region dead afterwards) ----
    half8 Uh[2][4], Ul[2][4];
    #pragma unroll
    for (int pt = 0; pt < 2; ++pt) {
        #pragma unroll
        for (int ks = 0; ks < 4; ++ks) {
            const int row  = pt * 16 + m15;
            const int coli = (4 * ks + q) ^ m15;
            Uh[pt][ks] = *(const half8*)(wbase + row * 512 + (coli << 4));
            Ul[pt][ks] = *(const half8*)(wbase + row * 512 + 256 + (coli << 4));
        }
    }

    // ---- j-loop: 6 comp-tiles x (2 px-tiles x 12 MFMAs); logp aliases u ----
    float* lp = (float*)wbase;   // [96][33] f32 = 12672 B < 16384
    #pragma unroll 2
    for (int t = 0; t < 6; ++t) {
        const _Float16* chp = Ch + (size_t)(16 * t + m15) * 128 + 8 * q;
        const _Float16* clp = Cl + (size_t)(16 * t + m15) * 128 + 8 * q;
        half8 Ah[4], Al[4];
        #pragma unroll
        for (int ks = 0; ks < 4; ++ks) {
            Ah[ks] = *(const half8*)(chp + 32 * ks);
            Al[ks] = *(const half8*)(clp + 32 * ks);
        }
        f32x4 a0 = {0.f, 0.f, 0.f, 0.f}, a1 = a0;
        #pragma unroll
        for (int ks = 0; ks < 4; ++ks) {
            a0 = __builtin_amdgcn_mfma_f32_16x16x32_f16(Ah[ks], Uh[0][ks], a0, 0, 0, 0);
            a1 = __builtin_amdgcn_mfma_f32_16x16x32_f16(Ah[ks], Uh[1][ks], a1, 0, 0, 0);
        }
        #pragma unroll
        for (int ks = 0; ks < 4; ++ks) {
            a0 = __builtin_amdgcn_mfma_f32_16x16x32_f16(Ah[ks], Ul[0][ks], a0, 0, 0, 0);
            a1 = __builtin_amdgcn_mfma_f32_16x16x32_f16(Ah[ks], Ul[1][ks], a1, 0, 0, 0);
        }
        #pragma unroll
        for (int ks = 0; ks < 4; ++ks) {
            a0 = __builtin_amdgcn_mfma_f32_16x16x32_f16(Al[ks], Uh[0][ks], a0, 0, 0, 0);
            a1 = __builtin_amdgcn_mfma_f32_16x16x32_f16(Al[ks], Uh[1][ks], a1, 0, 0, 0);
        }
        #pragma unroll
        for (int rg = 0; rg < 4; ++rg) {
            const int j = 16 * t + 4 * q + rg;
            lp[j * 33 + m15]      = a0[rg];   // px-tile 0 -> cols 0..15
            lp[j * 33 + 16 + m15] = a1[rg];   // px-tile 1 -> cols 16..31
        }
    }

    // ---- epilogue (per-wave): max over P, LN over K, coalesced stores ----
    const int kbase = h * 10;            // h=0: k 0..9, h=1: k 10..18
    float mv[10];
    float S = 0.f;
    #pragma unroll
    for (int kk = 0; kk < 10; ++kk) {
        const int k = kbase + kk;
        float best = -3.4e38f;
        if (k < KK) {
            #pragma unroll
            for (int p = 0; p < PP; ++p) {
                const int j = 5 * k + p;
                best = fmaxf(best, lp[j * 33 + px] + cst[j]);
            }
            S += best;
        }
        mv[kk] = best;
    }
    S += __shfl_xor(S, 32);
    const float mum = S * (1.f / 19.f);
    float V = 0.f;
    #pragma unroll
    for (int kk = 0; kk < 10; ++kk) {
        if (kbase + kk < KK) { float t = mv[kk] - mum; V = fmaf(t, t, V); }
    }
    V += __shfl_xor(V, 32);
    const float rm = rsqrtf(V * (1.f / 19.f) + 1e-5f);

    float* op = out + (size_t)b * (KK * NPIX) + n0 + px;
    #pragma unroll
    for (int kk = 0; kk < 10; ++kk) {
        const int k = kbase + kk;
        if (k < KK)
            op[(size_t)k * NPIX] = (mv[kk] - mum) * rm * mask_w[k] + mask_b[k];
    }
}

extern "C" void kernel_launch(void* const* d_in, const int* in_sizes, int n_in,
                              void* d_out, int out_size, void* d_ws, size_t ws_size,
                              hipStream_t stream) {
    const float* base_feature = (const float*)d_in[0]; // [8, 64, 32768]
    const float* means        = (const float*)d_in[1]; // [19, 5, 64]
    const float* diagonal     = (const float*)d_in[2]; // [19, 5, 64]
    const float* feat_w       = (const float*)d_in[3]; // [64]
    const float* feat_b       = (const float*)d_in[4]; // [64]
    const float* mask_w       = (const float*)d_in[5]; // [19]
    const float* mask_b       = (const float*)d_in[6]; // [19]
    float* out = (float*)d_out;                        // [8, 19, 32768] fp32

    // ws layout: Ch[96*128] f16 | Cl[96*128] f16 | cst[96] f32 | scal[3] f32
    _Float16* Ch = (_Float16*)d_ws;
    _Float16* Cl = Ch + KPAD * 128;
    float* cst   = (float*)(Cl + KPAD * 128);
    float* scal  = cst + KPAD;

    gmm_prep<<<KPAD, 64, 0, stream>>>(means, diagonal, feat_w, feat_b, Ch, Cl, cst, scal);

    gmm_main<<<(BB * NPIX) / 64, 128, 0, stream>>>(
        base_feature, feat_w, feat_b, mask_w, mask_b, Ch, Cl, cst, scal, out);
}

// Round 5
// 155.394 us; speedup vs baseline: 1.0643x; 1.0643x over previous
//
#include <hip/hip_runtime.h>
#include <math.h>

// Problem constants (fixed by setup_inputs)
#define BB    8
#define DD    64
#define NPIX  32768
#define KK    19
#define PP    5
#define KP    95
#define KPAD  96

typedef _Float16 half8 __attribute__((ext_vector_type(8)));
typedef float f32x4 __attribute__((ext_vector_type(4)));

// ---------------------------------------------------------------------------
// Prep: bake coefficients into a single fp16 table (2-pass scheme: only u is
// split hi/lo; C is rounded once -- error ~5e-4 abs, well under threshold).
//   k-interleaved: C[j][2d] = mu_n*inv2 (x-term), C[j][2d+1] = -0.5*inv2 (x^2)
//   cst[j] = -0.5*sum(mu_n^2*inv2) - sum(log(scale)) - 32*log(2*pi)
//   j==95: zero pad row + scal = {sum(w^2), sum(w*b), sum(b^2)}
// ---------------------------------------------------------------------------
__global__ __launch_bounds__(64) void gmm_prep(
        const float* __restrict__ means, const float* __restrict__ diag,
        const float* __restrict__ feat_w, const float* __restrict__ feat_b,
        _Float16* __restrict__ Ch, float* __restrict__ cst,
        float* __restrict__ scal) {
    int j = blockIdx.x;
    int d = threadIdx.x;
    if (j < KP) {
        float mu = means[j * DD + d];
        float sc = diag[j * DD + d];
        float ss = mu * mu;
        #pragma unroll
        for (int off = 32; off; off >>= 1) ss += __shfl_xor(ss, off);
        float inv = 1.f / fmaxf(sqrtf(ss), 1e-12f);
        float mn = mu * inv;
        float i2 = 1.f / (sc * sc);
        Ch[j * 128 + 2 * d]     = (_Float16)(mn * i2);
        Ch[j * 128 + 2 * d + 1] = (_Float16)(-0.5f * i2);
        float c1 = mn * mn * i2;
        float c2 = logf(sc);
        #pragma unroll
        for (int off = 32; off; off >>= 1) {
            c1 += __shfl_xor(c1, off);
            c2 += __shfl_xor(c2, off);
        }
        if (d == 0) cst[j] = -0.5f * c1 - c2 - 58.8120661251f; // 32*ln(2*pi)
    } else {
        Ch[95 * 128 + 2 * d]     = (_Float16)0.f;
        Ch[95 * 128 + 2 * d + 1] = (_Float16)0.f;
        float w = feat_w[d], b = feat_b[d];
        float s0 = w * w, s1 = w * b, s2 = b * b;
        #pragma unroll
        for (int off = 32; off; off >>= 1) {
            s0 += __shfl_xor(s0, off);
            s1 += __shfl_xor(s1, off);
            s2 += __shfl_xor(s2, off);
        }
        if (d == 0) { cst[95] = 0.f; scal[0] = s0; scal[1] = s1; scal[2] = s2; }
    }
}

// ---------------------------------------------------------------------------
// Main: 256 thr = 4 independent waves, 16 px each. ZERO barriers.
//   lane = (px = lane&15, q = lane>>4). Lane owns d in {16ks + 4q + i}:
//   exactly the k-slots of its MFMA B-fragment -> u built in REGISTERS,
//   no LDS staging for u. Moments via 2 shfl_xor rounds (lanes sharing px).
//   j-loop: 6 tiles x 8 MFMAs (uh,ul passes), C-frags prefetched from the
//   24KB L1-resident table. logp -> wave-private LDS [96][17] for the
//   max/LN/store epilogue (k-split across quads).
// ---------------------------------------------------------------------------
__global__ __launch_bounds__(256, 4) void gmm_main(
        const float* __restrict__ bf,
        const float* __restrict__ feat_w, const float* __restrict__ feat_b,
        const float* __restrict__ mask_w, const float* __restrict__ mask_b,
        const _Float16* __restrict__ Ch, const float* __restrict__ cst,
        const float* __restrict__ scal, float* __restrict__ out) {
    __shared__ float lds[4][96 * 17];    // 26112 B, wave-private slices

    const int tid  = threadIdx.x;
    const int w    = tid >> 6;
    const int lane = tid & 63;
    const int px   = lane & 15;
    const int q    = lane >> 4;
    const int bidx = blockIdx.x;
    const int b    = bidx >> 9;                       // 512 blocks per image
    const int n0   = ((bidx & 511) << 6) + (w << 4);  // wave's first pixel
    float* lp = lds[w];

    // ---- global x loads: lane's 16 d's (16 consecutive px per d-row) ----
    const float* xp = bf + (size_t)b * (DD * NPIX) + n0 + px;
    float xs[16];
    #pragma unroll
    for (int ks = 0; ks < 4; ++ks)
        #pragma unroll
        for (int i = 0; i < 4; ++i)
            xs[ks * 4 + i] = xp[(size_t)(ks * 16 + q * 4 + i) * NPIX];

    // per-lane LN weights for its 16 d's (L1-hot vector loads)
    float4 wv[4], bv[4];
    #pragma unroll
    for (int ks = 0; ks < 4; ++ks) {
        wv[ks] = *(const float4*)(feat_w + ks * 16 + q * 4);
        bv[ks] = *(const float4*)(feat_b + ks * 16 + q * 4);
    }

    // ---- moments: partials over 16 d's, combine 4 lanes sharing px ----
    float S1 = 0.f, S2 = 0.f, S3 = 0.f, S4 = 0.f, S5 = 0.f;
    #pragma unroll
    for (int ks = 0; ks < 4; ++ks) {
        #pragma unroll
        for (int i = 0; i < 4; ++i) {
            float wd = ((const float*)&wv[ks])[i];
            float bd = ((const float*)&bv[ks])[i];
            float x  = xs[ks * 4 + i];
            float t  = wd * x;
            S1 += x;
            S2 = fmaf(x, x, S2);
            S3 = fmaf(t, t, S3);
            S4 = fmaf(t, wd, S4);
            S5 = fmaf(t, bd, S5);
        }
    }
    S1 += __shfl_xor(S1, 16); S1 += __shfl_xor(S1, 32);
    S2 += __shfl_xor(S2, 16); S2 += __shfl_xor(S2, 32);
    S3 += __shfl_xor(S3, 16); S3 += __shfl_xor(S3, 32);
    S4 += __shfl_xor(S4, 16); S4 += __shfl_xor(S4, 32);
    S5 += __shfl_xor(S5, 16); S5 += __shfl_xor(S5, 32);

    const float W2 = scal[0], WB = scal[1], B2 = scal[2];
    float mu  = S1 * (1.f / 64.f);
    float var = fmaxf(S2 * (1.f / 64.f) - mu * mu, 0.f);
    float r   = rsqrtf(var + 1e-5f);
    float Sy2 = r * r * (S3 - 2.f * mu * S4 + mu * mu * W2)
              + 2.f * r * (S5 - mu * WB) + B2;
    float invn  = 1.f / fmaxf(sqrtf(fmaxf(Sy2, 0.f)), 1e-12f);
    float alpha = invn * r;   // u_d = alpha*w_d*x_d + (invn*b_d - alpha*mu*w_d)
    float e = invn;
    float f = -alpha * mu;

    // ---- build split-fp16 u B-fragments directly in registers ----
    half8 Uh[4], Ul[4];
    #pragma unroll
    for (int ks = 0; ks < 4; ++ks) {
        #pragma unroll
        for (int i = 0; i < 4; ++i) {
            float wd = ((const float*)&wv[ks])[i];
            float bd = ((const float*)&bv[ks])[i];
            float c  = fmaf(f, wd, e * bd);
            float u  = fmaf(alpha, wd * xs[ks * 4 + i], c);
            float us = u * u;
            _Float16 uh = (_Float16)u;  _Float16 ulo = (_Float16)(u  - (float)uh);
            _Float16 qh = (_Float16)us; _Float16 qlo = (_Float16)(us - (float)qh);
            Uh[ks][2 * i] = uh;  Uh[ks][2 * i + 1] = qh;
            Ul[ks][2 * i] = ulo; Ul[ks][2 * i + 1] = qlo;
        }
    }

    // ---- j-loop: 6 comp-tiles, 8 MFMAs each; C prefetched 1 tile ahead ----
    const _Float16* cb = Ch + (size_t)px * 128 + q * 8;  // row = 16t + px
    half8 Ac[4];
    #pragma unroll
    for (int ks = 0; ks < 4; ++ks) Ac[ks] = *(const half8*)(cb + ks * 32);
    float4 cc = *(const float4*)(cst + 4 * q);           // j = 16t + 4q + r

    #pragma unroll 2
    for (int t = 0; t < 6; ++t) {
        half8 An[4];
        float4 cn;
        if (t < 5) {
            const _Float16* nb = cb + (size_t)(16 * (t + 1)) * 128;
            #pragma unroll
            for (int ks = 0; ks < 4; ++ks) An[ks] = *(const half8*)(nb + ks * 32);
            cn = *(const float4*)(cst + 16 * (t + 1) + 4 * q);
        }
        f32x4 acc = {0.f, 0.f, 0.f, 0.f};
        #pragma unroll
        for (int ks = 0; ks < 4; ++ks)
            acc = __builtin_amdgcn_mfma_f32_16x16x32_f16(Ac[ks], Uh[ks], acc, 0, 0, 0);
        #pragma unroll
        for (int ks = 0; ks < 4; ++ks)
            acc = __builtin_amdgcn_mfma_f32_16x16x32_f16(Ac[ks], Ul[ks], acc, 0, 0, 0);
        #pragma unroll
        for (int rg = 0; rg < 4; ++rg)
            lp[(16 * t + 4 * q + rg) * 17 + px] = acc[rg] + ((const float*)&cc)[rg];
        if (t < 5) {
            #pragma unroll
            for (int ks = 0; ks < 4; ++ks) Ac[ks] = An[ks];
            cc = cn;
        }
    }

    // ---- epilogue: quad q owns k in [5q, 5q+5) (q=3: 15..18) ----
    const int kb = q * 5;
    float mv[5];
    float S = 0.f;
    #pragma unroll
    for (int kk = 0; kk < 5; ++kk) {
        const int k = kb + kk;
        float best = -3.4e38f;
        if (k < KK) {
            #pragma unroll
            for (int p = 0; p < PP; ++p)
                best = fmaxf(best, lp[(5 * k + p) * 17 + px]);
            S += best;
        }
        mv[kk] = best;
    }
    S += __shfl_xor(S, 16); S += __shfl_xor(S, 32);
    const float mum = S * (1.f / 19.f);
    float V = 0.f;
    #pragma unroll
    for (int kk = 0; kk < 5; ++kk) {
        if (kb + kk < KK) { float t = mv[kk] - mum; V = fmaf(t, t, V); }
    }
    V += __shfl_xor(V, 16); V += __shfl_xor(V, 32);
    const float rm = rsqrtf(V * (1.f / 19.f) + 1e-5f);

    float* op = out + (size_t)b * (KK * NPIX) + n0 + px;
    #pragma unroll
    for (int kk = 0; kk < 5; ++kk) {
        const int k = kb + kk;
        if (k < KK)
            op[(size_t)k * NPIX] = (mv[kk] - mum) * rm * mask_w[k] + mask_b[k];
    }
}

extern "C" void kernel_launch(void* const* d_in, const int* in_sizes, int n_in,
                              void* d_out, int out_size, void* d_ws, size_t ws_size,
                              hipStream_t stream) {
    const float* base_feature = (const float*)d_in[0]; // [8, 64, 32768]
    const float* means        = (const float*)d_in[1]; // [19, 5, 64]
    const float* diagonal     = (const float*)d_in[2]; // [19, 5, 64]
    const float* feat_w       = (const float*)d_in[3]; // [64]
    const float* feat_b       = (const float*)d_in[4]; // [64]
    const float* mask_w       = (const float*)d_in[5]; // [19]
    const float* mask_b       = (const float*)d_in[6]; // [19]
    float* out = (float*)d_out;                        // [8, 19, 32768] fp32

    // ws layout: Ch[96*128] f16 | cst[96] f32 | scal[3] f32
    _Float16* Ch = (_Float16*)d_ws;
    float* cst   = (float*)(Ch + KPAD * 128);
    float* scal  = cst + KPAD;

    gmm_prep<<<KPAD, 64, 0, stream>>>(means, diagonal, feat_w, feat_b, Ch, cst, scal);

    gmm_main<<<(BB * NPIX) / 64, 256, 0, stream>>>(
        base_feature, feat_w, feat_b, mask_w, mask_b, Ch, cst, scal, out);
}

// Round 7
// 138.231 us; speedup vs baseline: 1.1965x; 1.1242x over previous
//
#include <hip/hip_runtime.h>
#include <math.h>

// Problem constants (fixed by setup_inputs)
#define BB    8
#define DD    64
#define NPIX  32768
#define KK    19
#define PP    5
#define KP    95
#define KPAD  96

typedef _Float16 half8  __attribute__((ext_vector_type(8)));
typedef __fp16   half2t __attribute__((ext_vector_type(2)));   // cvt_pkrtz return type
typedef float    f32x4  __attribute__((ext_vector_type(4)));

union H8 { half8 v; half2t p[4]; };

// ---------------------------------------------------------------------------
// Prep (unchanged, verified): single fp16 C table, k-interleaved
//   C[j][2d] = mu_n*inv2, C[j][2d+1] = -0.5*inv2 ; cst[j]; j=95 zero row;
//   scal = {sum(w^2), sum(w*b), sum(b^2)}.
// ---------------------------------------------------------------------------
__global__ __launch_bounds__(64) void gmm_prep(
        const float* __restrict__ means, const float* __restrict__ diag,
        const float* __restrict__ feat_w, const float* __restrict__ feat_b,
        _Float16* __restrict__ Ch, float* __restrict__ cst,
        float* __restrict__ scal) {
    int j = blockIdx.x;
    int d = threadIdx.x;
    if (j < KP) {
        float mu = means[j * DD + d];
        float sc = diag[j * DD + d];
        float ss = mu * mu;
        #pragma unroll
        for (int off = 32; off; off >>= 1) ss += __shfl_xor(ss, off);
        float inv = 1.f / fmaxf(sqrtf(ss), 1e-12f);
        float mn = mu * inv;
        float i2 = 1.f / (sc * sc);
        Ch[j * 128 + 2 * d]     = (_Float16)(mn * i2);
        Ch[j * 128 + 2 * d + 1] = (_Float16)(-0.5f * i2);
        float c1 = mn * mn * i2;
        float c2 = logf(sc);
        #pragma unroll
        for (int off = 32; off; off >>= 1) {
            c1 += __shfl_xor(c1, off);
            c2 += __shfl_xor(c2, off);
        }
        if (d == 0) cst[j] = -0.5f * c1 - c2 - 58.8120661251f; // 32*ln(2*pi)
    } else {
        Ch[95 * 128 + 2 * d]     = (_Float16)0.f;
        Ch[95 * 128 + 2 * d + 1] = (_Float16)0.f;
        float w = feat_w[d], b = feat_b[d];
        float s0 = w * w, s1 = w * b, s2 = b * b;
        #pragma unroll
        for (int off = 32; off; off >>= 1) {
            s0 += __shfl_xor(s0, off);
            s1 += __shfl_xor(s1, off);
            s2 += __shfl_xor(s2, off);
        }
        if (d == 0) { cst[95] = 0.f; scal[0] = s0; scal[1] = s1; scal[2] = s2; }
    }
}

// ---------------------------------------------------------------------------
// Main: 256 thr = 4 independent waves, 32 px each (2 MFMA B-tiles). ZERO
// barriers. launch_bounds(256,2): 256-VGPR budget so fragments live in real
// VGPRs (r4/r5 regression root-caused to AGPR shuffling at tight budgets).
//   lane = (m15 = px-in-tile, q = k-quad). Lane owns d in {16ks+4q+i} for
//   px {n0+m15, n0+16+m15}: u fragments built IN REGISTERS via cvt_pkrtz.
//   j-loop: 6 tiles x (2 px-tiles x 8 MFMAs), C prefetched 1 tile ahead,
//   cst folded into the LDS store. Epilogue per-wave, k-halves split on
//   opposite LDS bank parity (2-way conflicts = free).
// ---------------------------------------------------------------------------
#define LPS 98   // f32 stride per px row: even (8B-aligned float2 stores) + pad

__global__ __launch_bounds__(256, 2) void gmm_main(
        const float* __restrict__ bf,
        const float* __restrict__ feat_w, const float* __restrict__ feat_b,
        const float* __restrict__ mask_w, const float* __restrict__ mask_b,
        const _Float16* __restrict__ Ch, const float* __restrict__ cst,
        const float* __restrict__ scal, float* __restrict__ out) {
    __shared__ float lds[4][32 * LPS];   // 50176 B, wave-private slices

    const int tid  = threadIdx.x;
    const int w    = tid >> 6;
    const int lane = tid & 63;
    const int m15  = lane & 15;
    const int q    = lane >> 4;
    const int bidx = blockIdx.x;
    const int b    = bidx >> 8;                        // 256 blocks per image
    const int n0   = ((bidx & 255) << 7) + (w << 5);   // wave's 32 pixels
    float* lp = lds[w];

    // ---- global x loads: 2 pixels (tiles) x lane's 16 d's ----
    const float* xp = bf + (size_t)b * (DD * NPIX) + n0 + m15;
    float xs0[16], xs1[16];
    #pragma unroll
    for (int ks = 0; ks < 4; ++ks)
        #pragma unroll
        for (int i = 0; i < 4; ++i) {
            const size_t off = (size_t)(ks * 16 + q * 4 + i) * NPIX;
            xs0[ks * 4 + i] = xp[off];
            xs1[ks * 4 + i] = xp[off + 16];
        }

    float4 wv[4], bv[4];
    #pragma unroll
    for (int ks = 0; ks < 4; ++ks) {
        wv[ks] = *(const float4*)(feat_w + ks * 16 + q * 4);
        bv[ks] = *(const float4*)(feat_b + ks * 16 + q * 4);
    }

    // ---- moments for both pixels; combine the 4 q-lanes per px ----
    float S1a = 0.f, S2a = 0.f, S3a = 0.f, S4a = 0.f, S5a = 0.f;
    float S1b = 0.f, S2b = 0.f, S3b = 0.f, S4b = 0.f, S5b = 0.f;
    #pragma unroll
    for (int ks = 0; ks < 4; ++ks)
        #pragma unroll
        for (int i = 0; i < 4; ++i) {
            float wd = ((const float*)&wv[ks])[i];
            float bd = ((const float*)&bv[ks])[i];
            float xa = xs0[ks * 4 + i], xb = xs1[ks * 4 + i];
            float ta = wd * xa, tb = wd * xb;
            S1a += xa; S2a = fmaf(xa, xa, S2a); S3a = fmaf(ta, ta, S3a);
            S4a = fmaf(ta, wd, S4a); S5a = fmaf(ta, bd, S5a);
            S1b += xb; S2b = fmaf(xb, xb, S2b); S3b = fmaf(tb, tb, S3b);
            S4b = fmaf(tb, wd, S4b); S5b = fmaf(tb, bd, S5b);
        }
    S1a += __shfl_xor(S1a, 16); S1a += __shfl_xor(S1a, 32);
    S2a += __shfl_xor(S2a, 16); S2a += __shfl_xor(S2a, 32);
    S3a += __shfl_xor(S3a, 16); S3a += __shfl_xor(S3a, 32);
    S4a += __shfl_xor(S4a, 16); S4a += __shfl_xor(S4a, 32);
    S5a += __shfl_xor(S5a, 16); S5a += __shfl_xor(S5a, 32);
    S1b += __shfl_xor(S1b, 16); S1b += __shfl_xor(S1b, 32);
    S2b += __shfl_xor(S2b, 16); S2b += __shfl_xor(S2b, 32);
    S3b += __shfl_xor(S3b, 16); S3b += __shfl_xor(S3b, 32);
    S4b += __shfl_xor(S4b, 16); S4b += __shfl_xor(S4b, 32);
    S5b += __shfl_xor(S5b, 16); S5b += __shfl_xor(S5b, 32);

    const float W2 = scal[0], WB = scal[1], B2 = scal[2];
    float al0, e0, f0, al1, e1, f1;
    {
        float mu  = S1a * (1.f / 64.f);
        float var = fmaxf(S2a * (1.f / 64.f) - mu * mu, 0.f);
        float r   = rsqrtf(var + 1e-5f);
        float Sy2 = r * r * (S3a - 2.f * mu * S4a + mu * mu * W2)
                  + 2.f * r * (S5a - mu * WB) + B2;
        float invn = 1.f / fmaxf(sqrtf(fmaxf(Sy2, 0.f)), 1e-12f);
        al0 = invn * r; e0 = invn; f0 = -al0 * mu;
    }
    {
        float mu  = S1b * (1.f / 64.f);
        float var = fmaxf(S2b * (1.f / 64.f) - mu * mu, 0.f);
        float r   = rsqrtf(var + 1e-5f);
        float Sy2 = r * r * (S3b - 2.f * mu * S4b + mu * mu * W2)
                  + 2.f * r * (S5b - mu * WB) + B2;
        float invn = 1.f / fmaxf(sqrtf(fmaxf(Sy2, 0.f)), 1e-12f);
        al1 = invn * r; e1 = invn; f1 = -al1 * mu;
    }

    // ---- build split-fp16 u B-fragments in registers (packed cvt) ----
    H8 Uh[2][4], Ul[2][4];
    #pragma unroll
    for (int ks = 0; ks < 4; ++ks) {
        #pragma unroll
        for (int i = 0; i < 4; ++i) {
            float wd = ((const float*)&wv[ks])[i];
            float bd = ((const float*)&bv[ks])[i];
            float c0 = fmaf(f0, wd, e0 * bd);
            float c1 = fmaf(f1, wd, e1 * bd);
            float u0 = fmaf(al0, wd * xs0[ks * 4 + i], c0);
            float u1 = fmaf(al1, wd * xs1[ks * 4 + i], c1);
            float q0 = u0 * u0, q1 = u1 * u1;
            half2t h0 = __builtin_amdgcn_cvt_pkrtz(u0, q0);   // [u, usq] hi
            half2t h1 = __builtin_amdgcn_cvt_pkrtz(u1, q1);
            half2t l0 = __builtin_amdgcn_cvt_pkrtz(u0 - (float)h0[0], q0 - (float)h0[1]);
            half2t l1 = __builtin_amdgcn_cvt_pkrtz(u1 - (float)h1[0], q1 - (float)h1[1]);
            Uh[0][ks].p[i] = h0; Ul[0][ks].p[i] = l0;
            Uh[1][ks].p[i] = h1; Ul[1][ks].p[i] = l1;
        }
    }

    // ---- j-loop: 6 comp-tiles x 16 MFMAs; C + cst prefetched 1 ahead ----
    const _Float16* cb = Ch + (size_t)m15 * 128 + q * 8;   // A row = 16t + m15
    half8 Ac[4];
    #pragma unroll
    for (int ks = 0; ks < 4; ++ks) Ac[ks] = *(const half8*)(cb + ks * 32);
    float4 cc = *(const float4*)(cst + 4 * q);             // j = 16t + 4q + rg

    #pragma unroll 2
    for (int t = 0; t < 6; ++t) {
        half8 An[4];
        float4 cn;
        if (t < 5) {
            const _Float16* nb = cb + (size_t)(16 * (t + 1)) * 128;
            #pragma unroll
            for (int ks = 0; ks < 4; ++ks) An[ks] = *(const half8*)(nb + ks * 32);
            cn = *(const float4*)(cst + 16 * (t + 1) + 4 * q);
        }
        f32x4 a0 = {0.f, 0.f, 0.f, 0.f}, a1 = a0;
        #pragma unroll
        for (int ks = 0; ks < 4; ++ks) {
            a0 = __builtin_amdgcn_mfma_f32_16x16x32_f16(Ac[ks], Uh[0][ks].v, a0, 0, 0, 0);
            a1 = __builtin_amdgcn_mfma_f32_16x16x32_f16(Ac[ks], Uh[1][ks].v, a1, 0, 0, 0);
        }
        #pragma unroll
        for (int ks = 0; ks < 4; ++ks) {
            a0 = __builtin_amdgcn_mfma_f32_16x16x32_f16(Ac[ks], Ul[0][ks].v, a0, 0, 0, 0);
            a1 = __builtin_amdgcn_mfma_f32_16x16x32_f16(Ac[ks], Ul[1][ks].v, a1, 0, 0, 0);
        }
        // logp (+cst) -> LDS, float2 stores (8B aligned: LPS even, j0 even)
        {
            const int j0 = 16 * t + 4 * q;
            float2 v00 = make_float2(a0[0] + cc[0], a0[1] + cc[1]);
            float2 v01 = make_float2(a0[2] + cc[2], a0[3] + cc[3]);
            float2 v10 = make_float2(a1[0] + cc[0], a1[1] + cc[1]);
            float2 v11 = make_float2(a1[2] + cc[2], a1[3] + cc[3]);
            *(float2*)(lp + m15 * LPS + j0)            = v00;
            *(float2*)(lp + m15 * LPS + j0 + 2)        = v01;
            *(float2*)(lp + (16 + m15) * LPS + j0)     = v10;
            *(float2*)(lp + (16 + m15) * LPS + j0 + 2) = v11;
        }
        if (t < 5) {
            #pragma unroll
            for (int ks = 0; ks < 4; ++ks) Ac[ks] = An[ks];
            cc = cn;
        }
    }

    // ---- epilogue: lane = (px2 = lane&31, h = lane>>5). h=0: k 0..8, 
    // h=1: k 9..18 (j base 45 -> opposite bank parity; 2-way = free) ----
    const int px2 = lane & 31;
    const int h   = lane >> 5;
    const int kb  = h ? 9 : 0;
    const int ke  = h ? 19 : 9;
    const float* rowp = lp + px2 * LPS;
    float mv[10];
    float S = 0.f;
    #pragma unroll
    for (int kk = 0; kk < 10; ++kk) {
        const int k = kb + kk;
        float best = -3.4e38f;
        if (k < ke) {
            #pragma unroll
            for (int p = 0; p < PP; ++p)
                best = fmaxf(best, rowp[5 * k + p]);
            S += best;
        }
        mv[kk] = best;
    }
    S += __shfl_xor(S, 32);
    const float mum = S * (1.f / 19.f);
    float V = 0.f;
    #pragma unroll
    for (int kk = 0; kk < 10; ++kk) {
        if (kb + kk < ke) { float t = mv[kk] - mum; V = fmaf(t, t, V); }
    }
    V += __shfl_xor(V, 32);
    const float rm = rsqrtf(V * (1.f / 19.f) + 1e-5f);

    float* op = out + (size_t)b * (KK * NPIX) + n0 + px2;
    #pragma unroll
    for (int kk = 0; kk < 10; ++kk) {
        const int k = kb + kk;
        if (k < ke)
            op[(size_t)k * NPIX] = (mv[kk] - mum) * rm * mask_w[k] + mask_b[k];
    }
}

extern "C" void kernel_launch(void* const* d_in, const int* in_sizes, int n_in,
                              void* d_out, int out_size, void* d_ws, size_t ws_size,
                              hipStream_t stream) {
    const float* base_feature = (const float*)d_in[0]; // [8, 64, 32768]
    const float* means        = (const float*)d_in[1]; // [19, 5, 64]
    const float* diagonal     = (const float*)d_in[2]; // [19, 5, 64]
    const float* feat_w       = (const float*)d_in[3]; // [64]
    const float* feat_b       = (const float*)d_in[4]; // [64]
    const float* mask_w       = (const float*)d_in[5]; // [19]
    const float* mask_b       = (const float*)d_in[6]; // [19]
    float* out = (float*)d_out;                        // [8, 19, 32768] fp32

    // ws layout: Ch[96*128] f16 | cst[96] f32 | scal[3] f32
    _Float16* Ch = (_Float16*)d_ws;
    float* cst   = (float*)(Ch + KPAD * 128);
    float* scal  = cst + KPAD;

    gmm_prep<<<KPAD, 64, 0, stream>>>(means, diagonal, feat_w, feat_b, Ch, cst, scal);

    gmm_main<<<(BB * NPIX) / 128, 256, 0, stream>>>(
        base_feature, feat_w, feat_b, mask_w, mask_b, Ch, cst, scal, out);
}